// Round 2
// baseline (361.572 us; speedup 1.0000x reference)
//
#include <hip/hip_runtime.h>
#include <hip/hip_bf16.h>

typedef __hip_bfloat16 bf16;
typedef __attribute__((ext_vector_type(8))) short short8;   // 8 bf16 = 4 VGPRs
typedef __attribute__((ext_vector_type(4))) short short4v;  // 4 bf16 = 2 VGPRs
typedef __attribute__((ext_vector_type(4))) float f32x4;    // MFMA C/D

#define BB 4
#define NN 2048
#define DD 256
#define HH 8
#define HD 32
#define BN (BB*NN)          // 8192
#define ELEMS (BN*DD)       // 2097152

// ---------------------------------------------------------------------------
// Scratch in module .bss (~25 MB).
// ---------------------------------------------------------------------------
__device__ int g_isf32;
__device__ __attribute__((aligned(256))) unsigned short g_qb [ELEMS]; // [bh][n][d] bf16 (pre-scaled)
__device__ __attribute__((aligned(256))) unsigned short g_kb [ELEMS]; // [bh][n][d] bf16
__device__ __attribute__((aligned(256))) unsigned short g_tA [ELEMS]; // [bh][d][n] bf16
__device__ __attribute__((aligned(256))) unsigned short g_tB [ELEMS]; // [bh][d][n] bf16
__device__ __attribute__((aligned(256))) float          g_acc[ELEMS]; // [b][n][D] f32
__device__ __attribute__((aligned(256))) unsigned short g_wt [4*DD*DD]; // W^T bf16 [mat][n][k]
__device__ __attribute__((aligned(256))) float g_bias[4*DD];
__device__ __attribute__((aligned(256))) float g_cf[HH*4];
__device__ __attribute__((aligned(256))) float g_invl[BB*HH*NN];      // cached 1/rowsum (pass 1)

__device__ __forceinline__ float b2f(unsigned short u) {
    union { unsigned int i; float f; } c; c.i = ((unsigned int)u) << 16; return c.f;
}
__device__ __forceinline__ unsigned short f2b(float f) {           // safe path
    bf16 h = __float2bfloat16(f);
    return *reinterpret_cast<unsigned short*>(&h);
}
// pack two f32 -> one u32 of two bf16 (RNE).  gfx950 has a 1-instr pk cvt.
#if __has_builtin(__builtin_amdgcn_cvt_pk_bf16_f32)
typedef __attribute__((ext_vector_type(2))) __bf16 bf16x2t;
__device__ __forceinline__ unsigned int pk2(float a, float b) {
    union { bf16x2t v; unsigned int u; } c;
    c.v = __builtin_amdgcn_cvt_pk_bf16_f32(a, b);
    return c.u;
}
#else
__device__ __forceinline__ unsigned int pk2(float a, float b) {
    unsigned int ua = __float_as_uint(a), ub = __float_as_uint(b);
    ua = (ua + 0x7FFFu + ((ua >> 16) & 1u)) >> 16;
    ub = (ub + 0x7FFFu + ((ub >> 16) & 1u)) & 0xFFFF0000u;
    return ua | ub;
}
#endif
__device__ __forceinline__ float ldin(const void* p, int i, int f32m) {
    return f32m ? ((const float*)p)[i] : b2f(((const unsigned short*)p)[i]);
}

// ---------------------------------------------------------------------------
// Kernel 0: dtype probe (unchanged — verified rounds 4-10).
// ---------------------------------------------------------------------------
__global__ __launch_bounds__(256) void probe_kernel(const void* __restrict__ x)
{
    __shared__ int cnt;
    if (threadIdx.x == 0) cnt = 0;
    __syncthreads();
    const unsigned short* u = (const unsigned short*)x;
    int w = 0;
    for (int i = threadIdx.x; i < 1024; i += 256) {
        const int e = (u[2 * i] >> 7) & 0xFF;
        if (e < 100 || e > 140) ++w;
    }
    atomicAdd(&cnt, w);
    __syncthreads();
    if (threadIdx.x == 0) g_isf32 = (cnt > 300) ? 1 : 0;
}

// ---------------------------------------------------------------------------
// Prep: transpose W[k][n] -> g_wt[mat][n][k] bf16; block(0,0) also preps
// biases + coeffs to f32.
// ---------------------------------------------------------------------------
__global__ __launch_bounds__(256) void prep_w_kernel(
    const void* W0, const void* W1, const void* W2, const void* W3,
    const void* bq, const void* bk, const void* bv, const void* bo,
    const void* coeffs)
{
    const int f32m = g_isf32;
    __shared__ unsigned short tile[64][65];
    const int mat = blockIdx.y;
    const void* W = (mat == 0) ? W0 : (mat == 1) ? W1 : (mat == 2) ? W2 : W3;
    const int k0 = (blockIdx.x >> 2) * 64;
    const int n0 = (blockIdx.x & 3) * 64;
    const int t  = threadIdx.x;

    if (blockIdx.x == 0 && blockIdx.y == 0) {
        g_bias[0 * DD + t] = ldin(bq, t, f32m);
        g_bias[1 * DD + t] = ldin(bk, t, f32m);
        g_bias[2 * DD + t] = ldin(bv, t, f32m);
        g_bias[3 * DD + t] = ldin(bo, t, f32m);
        if (t < 32) g_cf[t] = ldin(coeffs, t, f32m);
    }

    #pragma unroll
    for (int it = 0; it < 16; ++it) {
        const int flat = it * 256 + t;
        const int i = flat >> 6, j = flat & 63;
        tile[j][i] = f2b(ldin(W, (k0 + i) * DD + n0 + j, f32m));
    }
    __syncthreads();
    unsigned short* wt = g_wt + mat * DD * DD;
    #pragma unroll
    for (int it = 0; it < 16; ++it) {
        const int flat = it * 256 + t;
        const int nl = flat >> 6, kl = flat & 63;
        wt[(n0 + nl) * DD + k0 + kl] = tile[nl][kl];
    }
}

// ---------------------------------------------------------------------------
// Kernel 1: QKV projection GEMM (unchanged from r10).
// ---------------------------------------------------------------------------
__global__ __launch_bounds__(256) void qkv_gemm_kernel(const void* __restrict__ x)
{
    __shared__ unsigned short xs[64 * 32];
    __shared__ unsigned short wl[64 * 32];
    const int f32m = g_isf32;
    const int t  = threadIdx.x;
    const int w  = t >> 6, l = t & 63, lg = l >> 4, ln = l & 15;
    const int r0 = blockIdx.x * 64;
    const int n0 = blockIdx.y * 64;
    const int mat = blockIdx.z;
    const unsigned short* wt = g_wt + mat * DD * DD;
    const int sr = t >> 2, sc = (t & 3) * 8;

    f32x4 acc[4] = {{0,0,0,0},{0,0,0,0},{0,0,0,0},{0,0,0,0}};

    for (int kc = 0; kc < DD; kc += 32) {
        __syncthreads();
        if (f32m) {
            const float* src = (const float*)x + (size_t)(r0 + sr) * DD + kc + sc;
            const float4 a = *(const float4*)src;
            const float4 b = *(const float4*)(src + 4);
            union { uint4 v; unsigned short s[8]; } o;
            o.s[0]=f2b(a.x); o.s[1]=f2b(a.y); o.s[2]=f2b(a.z); o.s[3]=f2b(a.w);
            o.s[4]=f2b(b.x); o.s[5]=f2b(b.y); o.s[6]=f2b(b.z); o.s[7]=f2b(b.w);
            *(uint4*)(xs + sr * 32 + sc) = o.v;
        } else {
            *(uint4*)(xs + sr * 32 + sc) =
                *(const uint4*)((const unsigned short*)x + (size_t)(r0 + sr) * DD + kc + sc);
        }
        *(uint4*)(wl + sr * 32 + sc) =
            *(const uint4*)(wt + (size_t)(n0 + sr) * DD + kc + sc);
        __syncthreads();
        const short8 af = *(const short8*)(xs + (w * 16 + ln) * 32 + lg * 8);
        #pragma unroll
        for (int s = 0; s < 4; ++s) {
            const short8 bfr = *(const short8*)(wl + (s * 16 + ln) * 32 + lg * 8);
            acc[s] = __builtin_amdgcn_mfma_f32_16x16x32_bf16(af, bfr, acc[s], 0, 0, 0);
        }
    }

    const float QS = 0.17677669529663687f * 1.4426950408889634f; // scale*log2e
    #pragma unroll
    for (int s = 0; s < 4; ++s) {
        const int j = n0 + s * 16 + ln;
        const float bias = g_bias[mat * DD + j];
        const int h = j >> 5, dd = j & 31;
        #pragma unroll
        for (int r = 0; r < 4; ++r) {
            const int rn = r0 + w * 16 + lg * 4 + r;
            const int b = rn >> 11, n = rn & (NN - 1);
            const int bh = b * HH + h;
            const float val = acc[s][r] + bias;
            if (mat == 0) {
                g_qb[((size_t)bh * NN + n) * HD + dd] = f2b(val * QS);
            } else if (mat == 1) {
                g_kb[((size_t)bh * NN + n) * HD + dd] = f2b(val);
            } else {
                g_tA[((size_t)bh * HD + dd) * NN + n] = f2b(val);
                g_acc[(size_t)rn * DD + j] = g_cf[h * 4] * val;
            }
        }
    }
}

// ---------------------------------------------------------------------------
// Kernel 2 (r13): attention pass, latency-bound fix = 2x TLP.
// r12 post-mortem: manual load prefetch + unroll-2 regressed (+4us/pass on
// ALL kinds) — loads were never the exposed latency; the per-qi compute
// chain (mfma -> 8x exp(8cyc trans) -> pk -> mfma) is, and 4 waves/SIMD
// (grid 4096 waves vs 8192 capacity) can't cover it.  r13: Q-tile 64 -> 32
// queries/block => grid 2048 blocks x 4 waves = 8192 waves (100% of wave
// capacity), LDS 34.8 -> 17.4 KB (8 blocks/CU).  Loads back in-loop
// (r11 scheme, compiler-scheduled).  Kept from r12 (verified):
//  * KIND=0: row-sums on the matrix pipe (ones-A MFMA over packed pb),
//    1/rowsum cached to g_invl.
//  * KIND=1/2: skip all row-sum work, load cached invl.
//  * KIND=2: skip dead tout store.
// ---------------------------------------------------------------------------
template<int KIND>
__global__ __launch_bounds__(256, 6) void attn_pass_kernel(const int kidx, const int dir)
{
    __shared__ float osh[4][32][33];   // [wave][q][d] (+1 pad)  ~16.9 KB
    __shared__ float lsh[4][32];

    const unsigned short* __restrict__ tin  = dir ? g_tB : g_tA;
    unsigned short*       __restrict__ tout = dir ? g_tA : g_tB;

    const int tid = threadIdx.x;
    const int w   = tid >> 6;
    const int l   = tid & 63;
    const int lg  = l >> 4;
    const int ln  = l & 15;

    const int bh = blockIdx.x >> 6;    // b*H + h   (grid 32*64)
    const int qt = blockIdx.x & 63;
    const int h  = bh & (HH - 1);
    const int b  = bh >> 3;
    const int q0 = qt * 32;

    short8 qf[2];
    #pragma unroll
    for (int qi = 0; qi < 2; ++qi)
        qf[qi] = *(const short8*)(g_qb +
            ((size_t)bh * NN + q0 + qi * 16 + ln) * HD + lg * 8);

    const unsigned short* kb = g_kb + (size_t)bh * NN * HD;
    const unsigned short* tb = tin  + (size_t)bh * HD * NN;

    const f32x4 zero = {0.f, 0.f, 0.f, 0.f};
    f32x4 oacc[2][2];
    #pragma unroll
    for (int qi = 0; qi < 2; ++qi) { oacc[qi][0] = zero; oacc[qi][1] = zero; }
    f32x4 sacc[2];                                   // row-sum acc (KIND==0)
    if (KIND == 0) { sacc[0] = zero; sacc[1] = zero; }

#if __has_builtin(__builtin_amdgcn_mfma_f32_16x16x16bf16_1k)
    const short4v vone = {16256, 16256, 16256, 16256};   // bf16 1.0 x4

    for (int it = 0; it < 16; ++it) {
        const int k0 = it * 128 + w * 32;   // this wave's 32-key strip
        const short8 kf0 = *(const short8*)(kb + (size_t)(k0 + ln) * HD + lg * 8);
        const short8 kf1 = *(const short8*)(kb + (size_t)(k0 + 16 + ln) * HD + lg * 8);

        // T^T A-frags for K=16 PV: [c=key-chunk][hf=dim-half], 8B each
        short4v tf[2][2];
        #pragma unroll
        for (int c = 0; c < 2; ++c)
            #pragma unroll
            for (int hf = 0; hf < 2; ++hf)
                tf[c][hf] = *(const short4v*)(tb +
                    (size_t)(hf * 16 + ln) * NN + k0 + c * 16 + lg * 4);

        #pragma unroll
        for (int qi = 0; qi < 2; ++qi) {
            f32x4 s0 = __builtin_amdgcn_mfma_f32_16x16x32_bf16(kf0, qf[qi], zero, 0, 0, 0);
            f32x4 s1 = __builtin_amdgcn_mfma_f32_16x16x32_bf16(kf1, qf[qi], zero, 0, 0, 0);
            float p[8];
            #pragma unroll
            for (int r = 0; r < 4; ++r) {
                p[r]     = __builtin_amdgcn_exp2f(s0[r]);
                p[4 + r] = __builtin_amdgcn_exp2f(s1[r]);
            }
            union { unsigned int u[2]; short4v s; } pb0, pb1;
            pb0.u[0] = pk2(p[0], p[1]); pb0.u[1] = pk2(p[2], p[3]);
            pb1.u[0] = pk2(p[4], p[5]); pb1.u[1] = pk2(p[6], p[7]);
            if (KIND == 0) {     // row-sums on the matrix pipe
                sacc[qi] = __builtin_amdgcn_mfma_f32_16x16x16bf16_1k(vone, pb0.s, sacc[qi], 0, 0, 0);
                sacc[qi] = __builtin_amdgcn_mfma_f32_16x16x16bf16_1k(vone, pb1.s, sacc[qi], 0, 0, 0);
            }
            oacc[qi][0] = __builtin_amdgcn_mfma_f32_16x16x16bf16_1k(tf[0][0], pb0.s, oacc[qi][0], 0, 0, 0);
            oacc[qi][1] = __builtin_amdgcn_mfma_f32_16x16x16bf16_1k(tf[0][1], pb0.s, oacc[qi][1], 0, 0, 0);
            oacc[qi][0] = __builtin_amdgcn_mfma_f32_16x16x16bf16_1k(tf[1][0], pb1.s, oacc[qi][0], 0, 0, 0);
            oacc[qi][1] = __builtin_amdgcn_mfma_f32_16x16x16bf16_1k(tf[1][1], pb1.s, oacc[qi][1], 0, 0, 0);
        }
    }

    // wave-partial row-sums: every lane's sacc[qi][0] holds sum for q=qi*16+ln
    if (KIND == 0 && lg == 0) {
        #pragma unroll
        for (int qi = 0; qi < 2; ++qi) lsh[w][qi * 16 + ln] = sacc[qi][0];
    }
#else
    // fallback: r10's verified shuffle-transpose path (K=32 PV), scalar lsum
    float lsum[2] = {0.f, 0.f};
    for (int it = 0; it < 16; ++it) {
        const int k0 = it * 128 + w * 32;
        const short8 kf0 = *(const short8*)(kb + (size_t)(k0 + ln) * HD + lg * 8);
        const short8 kf1 = *(const short8*)(kb + (size_t)(k0 + 16 + ln) * HD + lg * 8);
        const short8 tf0 = *(const short8*)(tb + (size_t)ln * NN + k0 + lg * 8);
        const short8 tf1 = *(const short8*)(tb + (size_t)(ln + 16) * NN + k0 + lg * 8);
        #pragma unroll
        for (int qi = 0; qi < 2; ++qi) {
            f32x4 s0 = __builtin_amdgcn_mfma_f32_16x16x32_bf16(kf0, qf[qi], zero, 0, 0, 0);
            f32x4 s1 = __builtin_amdgcn_mfma_f32_16x16x32_bf16(kf1, qf[qi], zero, 0, 0, 0);
            float p[8];
            #pragma unroll
            for (int r = 0; r < 4; ++r) {
                p[r]     = __builtin_amdgcn_exp2f(s0[r]);
                p[4 + r] = __builtin_amdgcn_exp2f(s1[r]);
                lsum[qi] += p[r] + p[4 + r];
            }
            const unsigned int pk0 = pk2(p[0], p[1]);
            const unsigned int pk1 = pk2(p[2], p[3]);
            const unsigned int pk2v = pk2(p[4], p[5]);
            const unsigned int pk3 = pk2(p[6], p[7]);
            int bi[4];
            #pragma unroll
            for (int j = 0; j < 4; ++j) {
                const int srcLane = (((2 * lg + (j >> 1)) & 3) << 4) + ln;
                const int lo = __shfl((j & 1) ? (int)pk1 : (int)pk0, srcLane, 64);
                const int hi = __shfl((j & 1) ? (int)pk3 : (int)pk2v, srcLane, 64);
                bi[j] = (lg < 2) ? lo : hi;
            }
            union { int i[4]; short8 s; } pf;
            pf.i[0] = bi[0]; pf.i[1] = bi[1]; pf.i[2] = bi[2]; pf.i[3] = bi[3];
            oacc[qi][0] = __builtin_amdgcn_mfma_f32_16x16x32_bf16(tf0, pf.s, oacc[qi][0], 0, 0, 0);
            oacc[qi][1] = __builtin_amdgcn_mfma_f32_16x16x32_bf16(tf1, pf.s, oacc[qi][1], 0, 0, 0);
        }
    }
    if (KIND == 0) {
        #pragma unroll
        for (int qi = 0; qi < 2; ++qi) {
            lsum[qi] += __shfl_xor(lsum[qi], 16, 64);
            lsum[qi] += __shfl_xor(lsum[qi], 32, 64);
        }
        if (lg == 0) {
            #pragma unroll
            for (int qi = 0; qi < 2; ++qi) lsh[w][qi * 16 + ln] = lsum[qi];
        }
    }
#endif

    // store O^T wave-partials: row q = qi*16+ln, col d = hf*16+lg*4+r
    #pragma unroll
    for (int qi = 0; qi < 2; ++qi)
        #pragma unroll
        for (int hf = 0; hf < 2; ++hf)
            #pragma unroll
            for (int r = 0; r < 4; ++r)
                osh[w][qi * 16 + ln][hf * 16 + lg * 4 + r] = oacc[qi][hf][r];
    __syncthreads();

    // combine 4 wave-partials; thread t: q = t&31, dims (t>>5)*4 ..+3
    {
        const int q  = tid & 31;
        const int db = (tid >> 5) * 4;
        float invl;
        if (KIND == 0) {
            invl = 1.0f / (lsh[0][q] + lsh[1][q] + lsh[2][q] + lsh[3][q]);
            if (db == 0) g_invl[(size_t)bh * NN + q0 + q] = invl;
        } else {
            invl = g_invl[(size_t)bh * NN + q0 + q];
        }
        const float ck = g_cf[h * 4 + kidx];
        #pragma unroll
        for (int dd = 0; dd < 4; ++dd) {
            const int d = db + dd;
            const float val = (osh[0][q][d] + osh[1][q][d] +
                               osh[2][q][d] + osh[3][q][d]) * invl;
            if (KIND != 2)
                tout[((size_t)bh * HD + d) * NN + q0 + q] = f2b(val);
            float* ga = g_acc + ((size_t)(b * NN + q0 + q)) * DD + h * HD + d;
            *ga += ck * val;
        }
    }
}

// ---------------------------------------------------------------------------
// Kernel 3: output projection GEMM (unchanged).
// ---------------------------------------------------------------------------
__global__ __launch_bounds__(256) void out_gemm_kernel(void* __restrict__ out)
{
    __shared__ unsigned short xs[64 * 32];
    __shared__ unsigned short wl[64 * 32];
    const int f32m = g_isf32;
    const int t  = threadIdx.x;
    const int w  = t >> 6, l = t & 63, lg = l >> 4, ln = l & 15;
    const int r0 = blockIdx.x * 64;
    const int n0 = blockIdx.y * 64;
    const unsigned short* wt = g_wt + 3 * DD * DD;
    const int sr = t >> 2, sc = (t & 3) * 8;

    f32x4 acc[4] = {{0,0,0,0},{0,0,0,0},{0,0,0,0},{0,0,0,0}};

    for (int kc = 0; kc < DD; kc += 32) {
        __syncthreads();
        {
            const float* src = g_acc + (size_t)(r0 + sr) * DD + kc + sc;
            const float4 a = *(const float4*)src;
            const float4 b = *(const float4*)(src + 4);
            union { uint4 v; unsigned short s[8]; } o;
            o.s[0]=f2b(a.x); o.s[1]=f2b(a.y); o.s[2]=f2b(a.z); o.s[3]=f2b(a.w);
            o.s[4]=f2b(b.x); o.s[5]=f2b(b.y); o.s[6]=f2b(b.z); o.s[7]=f2b(b.w);
            *(uint4*)(xs + sr * 32 + sc) = o.v;
        }
        *(uint4*)(wl + sr * 32 + sc) =
            *(const uint4*)(wt + (size_t)(n0 + sr) * DD + kc + sc);
        __syncthreads();
        const short8 af = *(const short8*)(xs + (w * 16 + ln) * 32 + lg * 8);
        #pragma unroll
        for (int s = 0; s < 4; ++s) {
            const short8 bfr = *(const short8*)(wl + (s * 16 + ln) * 32 + lg * 8);
            acc[s] = __builtin_amdgcn_mfma_f32_16x16x32_bf16(af, bfr, acc[s], 0, 0, 0);
        }
    }

    #pragma unroll
    for (int s = 0; s < 4; ++s) {
        const int j = n0 + s * 16 + ln;
        const float bias = g_bias[3 * DD + j];
        #pragma unroll
        for (int r = 0; r < 4; ++r) {
            const int rn = r0 + w * 16 + lg * 4 + r;
            const float val = acc[s][r] + bias;
            if (f32m) ((float*)out)[(size_t)rn * DD + j] = val;
            else      ((bf16*)out)[(size_t)rn * DD + j] = __float2bfloat16(val);
        }
    }
}

// ---------------------------------------------------------------------------
extern "C" void kernel_launch(void* const* d_in, const int* in_sizes, int n_in,
                              void* d_out, int out_size, void* d_ws, size_t ws_size,
                              hipStream_t stream)
{
    const void* x      = d_in[0];
    const void* Wq     = d_in[1];
    const void* bq     = d_in[2];
    const void* Wk     = d_in[3];
    const void* bk     = d_in[4];
    const void* Wv     = d_in[5];
    const void* bv     = d_in[6];
    const void* Wo     = d_in[7];
    const void* bo     = d_in[8];
    const void* coeffs = d_in[9];
    (void)d_ws; (void)ws_size; (void)in_sizes; (void)n_in; (void)out_size;

    probe_kernel<<<1, 256, 0, stream>>>(x);

    prep_w_kernel<<<dim3(16, 4), 256, 0, stream>>>(Wq, Wk, Wv, Wo,
                                                   bq, bk, bv, bo, coeffs);

    qkv_gemm_kernel<<<dim3(128, 4, 3), 256, 0, stream>>>(x);

    const int agrid = (BB * HH) * (NN / 32);   // 32 * 64 = 2048 blocks
    attn_pass_kernel<0><<<agrid, 256, 0, stream>>>(1, 0); // tA -> tB, caches invl
    attn_pass_kernel<1><<<agrid, 256, 0, stream>>>(2, 1); // tB -> tA, uses invl
    attn_pass_kernel<2><<<agrid, 256, 0, stream>>>(3, 0); // tA -> (acc only)

    out_gemm_kernel<<<dim3(128, 4), 256, 0, stream>>>(d_out);
}

// Round 3
// 280.958 us; speedup vs baseline: 1.2869x; 1.2869x over previous
//
#include <hip/hip_runtime.h>
#include <hip/hip_bf16.h>

typedef __hip_bfloat16 bf16;
typedef __attribute__((ext_vector_type(8))) short short8;   // 8 bf16 = 4 VGPRs
typedef __attribute__((ext_vector_type(4))) short short4v;  // 4 bf16 = 2 VGPRs
typedef __attribute__((ext_vector_type(4))) float f32x4;    // MFMA C/D

#define BB 4
#define NN 2048
#define DD 256
#define HH 8
#define HD 32
#define BN (BB*NN)          // 8192
#define ELEMS (BN*DD)       // 2097152

// ---------------------------------------------------------------------------
// Scratch in module .bss (~25 MB).
// ---------------------------------------------------------------------------
__device__ int g_isf32;
__device__ __attribute__((aligned(256))) unsigned short g_qb [ELEMS]; // [bh][n][d] bf16 (pre-scaled)
__device__ __attribute__((aligned(256))) unsigned short g_kb [ELEMS]; // [bh][n][d] bf16
__device__ __attribute__((aligned(256))) unsigned short g_tA [ELEMS]; // [bh][d][n] bf16
__device__ __attribute__((aligned(256))) unsigned short g_tB [ELEMS]; // [bh][d][n] bf16
__device__ __attribute__((aligned(256))) float          g_acc[ELEMS]; // [b][n][D] f32
__device__ __attribute__((aligned(256))) unsigned short g_wt [4*DD*DD]; // W^T bf16 [mat][n][k]
__device__ __attribute__((aligned(256))) float g_bias[4*DD];
__device__ __attribute__((aligned(256))) float g_cf[HH*4];
__device__ __attribute__((aligned(256))) float g_invl[BB*HH*NN];      // cached 1/rowsum (pass 1)

__device__ __forceinline__ float b2f(unsigned short u) {
    union { unsigned int i; float f; } c; c.i = ((unsigned int)u) << 16; return c.f;
}
__device__ __forceinline__ unsigned short f2b(float f) {           // safe path
    bf16 h = __float2bfloat16(f);
    return *reinterpret_cast<unsigned short*>(&h);
}
// pack two f32 -> one u32 of two bf16 (RNE).  gfx950 has a 1-instr pk cvt.
#if __has_builtin(__builtin_amdgcn_cvt_pk_bf16_f32)
typedef __attribute__((ext_vector_type(2))) __bf16 bf16x2t;
__device__ __forceinline__ unsigned int pk2(float a, float b) {
    union { bf16x2t v; unsigned int u; } c;
    c.v = __builtin_amdgcn_cvt_pk_bf16_f32(a, b);
    return c.u;
}
#else
__device__ __forceinline__ unsigned int pk2(float a, float b) {
    unsigned int ua = __float_as_uint(a), ub = __float_as_uint(b);
    ua = (ua + 0x7FFFu + ((ua >> 16) & 1u)) >> 16;
    ub = (ub + 0x7FFFu + ((ub >> 16) & 1u)) & 0xFFFF0000u;
    return ua | ub;
}
#endif
__device__ __forceinline__ float ldin(const void* p, int i, int f32m) {
    return f32m ? ((const float*)p)[i] : b2f(((const unsigned short*)p)[i]);
}

// ---------------------------------------------------------------------------
// Kernel 0: dtype probe (unchanged — verified rounds 4-10).
// ---------------------------------------------------------------------------
__global__ __launch_bounds__(256) void probe_kernel(const void* __restrict__ x)
{
    __shared__ int cnt;
    if (threadIdx.x == 0) cnt = 0;
    __syncthreads();
    const unsigned short* u = (const unsigned short*)x;
    int w = 0;
    for (int i = threadIdx.x; i < 1024; i += 256) {
        const int e = (u[2 * i] >> 7) & 0xFF;
        if (e < 100 || e > 140) ++w;
    }
    atomicAdd(&cnt, w);
    __syncthreads();
    if (threadIdx.x == 0) g_isf32 = (cnt > 300) ? 1 : 0;
}

// ---------------------------------------------------------------------------
// Prep: transpose W[k][n] -> g_wt[mat][n][k] bf16; block(0,0) also preps
// biases + coeffs to f32.
// ---------------------------------------------------------------------------
__global__ __launch_bounds__(256) void prep_w_kernel(
    const void* W0, const void* W1, const void* W2, const void* W3,
    const void* bq, const void* bk, const void* bv, const void* bo,
    const void* coeffs)
{
    const int f32m = g_isf32;
    __shared__ unsigned short tile[64][65];
    const int mat = blockIdx.y;
    const void* W = (mat == 0) ? W0 : (mat == 1) ? W1 : (mat == 2) ? W2 : W3;
    const int k0 = (blockIdx.x >> 2) * 64;
    const int n0 = (blockIdx.x & 3) * 64;
    const int t  = threadIdx.x;

    if (blockIdx.x == 0 && blockIdx.y == 0) {
        g_bias[0 * DD + t] = ldin(bq, t, f32m);
        g_bias[1 * DD + t] = ldin(bk, t, f32m);
        g_bias[2 * DD + t] = ldin(bv, t, f32m);
        g_bias[3 * DD + t] = ldin(bo, t, f32m);
        if (t < 32) g_cf[t] = ldin(coeffs, t, f32m);
    }

    #pragma unroll
    for (int it = 0; it < 16; ++it) {
        const int flat = it * 256 + t;
        const int i = flat >> 6, j = flat & 63;
        tile[j][i] = f2b(ldin(W, (k0 + i) * DD + n0 + j, f32m));
    }
    __syncthreads();
    unsigned short* wt = g_wt + mat * DD * DD;
    #pragma unroll
    for (int it = 0; it < 16; ++it) {
        const int flat = it * 256 + t;
        const int nl = flat >> 6, kl = flat & 63;
        wt[(n0 + nl) * DD + k0 + kl] = tile[nl][kl];
    }
}

// ---------------------------------------------------------------------------
// Kernel 1: QKV projection GEMM (unchanged from r10).
// ---------------------------------------------------------------------------
__global__ __launch_bounds__(256) void qkv_gemm_kernel(const void* __restrict__ x)
{
    __shared__ unsigned short xs[64 * 32];
    __shared__ unsigned short wl[64 * 32];
    const int f32m = g_isf32;
    const int t  = threadIdx.x;
    const int w  = t >> 6, l = t & 63, lg = l >> 4, ln = l & 15;
    const int r0 = blockIdx.x * 64;
    const int n0 = blockIdx.y * 64;
    const int mat = blockIdx.z;
    const unsigned short* wt = g_wt + mat * DD * DD;
    const int sr = t >> 2, sc = (t & 3) * 8;

    f32x4 acc[4] = {{0,0,0,0},{0,0,0,0},{0,0,0,0},{0,0,0,0}};

    for (int kc = 0; kc < DD; kc += 32) {
        __syncthreads();
        if (f32m) {
            const float* src = (const float*)x + (size_t)(r0 + sr) * DD + kc + sc;
            const float4 a = *(const float4*)src;
            const float4 b = *(const float4*)(src + 4);
            union { uint4 v; unsigned short s[8]; } o;
            o.s[0]=f2b(a.x); o.s[1]=f2b(a.y); o.s[2]=f2b(a.z); o.s[3]=f2b(a.w);
            o.s[4]=f2b(b.x); o.s[5]=f2b(b.y); o.s[6]=f2b(b.z); o.s[7]=f2b(b.w);
            *(uint4*)(xs + sr * 32 + sc) = o.v;
        } else {
            *(uint4*)(xs + sr * 32 + sc) =
                *(const uint4*)((const unsigned short*)x + (size_t)(r0 + sr) * DD + kc + sc);
        }
        *(uint4*)(wl + sr * 32 + sc) =
            *(const uint4*)(wt + (size_t)(n0 + sr) * DD + kc + sc);
        __syncthreads();
        const short8 af = *(const short8*)(xs + (w * 16 + ln) * 32 + lg * 8);
        #pragma unroll
        for (int s = 0; s < 4; ++s) {
            const short8 bfr = *(const short8*)(wl + (s * 16 + ln) * 32 + lg * 8);
            acc[s] = __builtin_amdgcn_mfma_f32_16x16x32_bf16(af, bfr, acc[s], 0, 0, 0);
        }
    }

    const float QS = 0.17677669529663687f * 1.4426950408889634f; // scale*log2e
    #pragma unroll
    for (int s = 0; s < 4; ++s) {
        const int j = n0 + s * 16 + ln;
        const float bias = g_bias[mat * DD + j];
        const int h = j >> 5, dd = j & 31;
        #pragma unroll
        for (int r = 0; r < 4; ++r) {
            const int rn = r0 + w * 16 + lg * 4 + r;
            const int b = rn >> 11, n = rn & (NN - 1);
            const int bh = b * HH + h;
            const float val = acc[s][r] + bias;
            if (mat == 0) {
                g_qb[((size_t)bh * NN + n) * HD + dd] = f2b(val * QS);
            } else if (mat == 1) {
                g_kb[((size_t)bh * NN + n) * HD + dd] = f2b(val);
            } else {
                g_tA[((size_t)bh * HD + dd) * NN + n] = f2b(val);
                g_acc[(size_t)rn * DD + j] = g_cf[h * 4] * val;
            }
        }
    }
}

// ---------------------------------------------------------------------------
// Kernel 2 (r14): attention pass.  r11 structure (64-query tile, grid 1024,
// in-loop compiler-scheduled loads) + doubled per-wave ILP: each wave now
// processes 64 keys/iteration (8 iterations) instead of 32/16.  r12/r13
// post-mortems showed the kernel is intra-wave latency-bound (per-SIMD issue
// ~20% on both pipes; removing VALU work gains ~0; forced-low VGPR
// serialization catastrophic).  Doubling independent mfma->exp->pk->mfma
// chains per loop body is the matching fix.  __launch_bounds__(256,4) caps
// VGPR at 128 = the 4-waves/SIMD budget (LDS already caps there).
// KIND specialization kept (risk-free work removal):
//  * KIND=0: scalar lsum exactly as r11 (verified numerics); stores 1/rowsum.
//  * KIND=1/2: skip all row-sum work, load cached invl.
//  * KIND=2: skip dead tout store (-4MB writes).
// ---------------------------------------------------------------------------
template<int KIND>
__global__ __launch_bounds__(256, 4) void attn_pass_kernel(const int kidx, const int dir)
{
    __shared__ float osh[4][64][33];   // [wave][q][d] (+1 pad)
    __shared__ float lsh[4][64];

    const unsigned short* __restrict__ tin  = dir ? g_tB : g_tA;
    unsigned short*       __restrict__ tout = dir ? g_tA : g_tB;

    const int tid = threadIdx.x;
    const int w   = tid >> 6;
    const int l   = tid & 63;
    const int lg  = l >> 4;
    const int ln  = l & 15;

    const int bh = blockIdx.x >> 5;    // b*H + h   (grid 32*32)
    const int qt = blockIdx.x & 31;
    const int h  = bh & (HH - 1);
    const int b  = bh >> 3;
    const int q0 = qt * 64;

    short8 qf[4];
    #pragma unroll
    for (int qi = 0; qi < 4; ++qi)
        qf[qi] = *(const short8*)(g_qb +
            ((size_t)bh * NN + q0 + qi * 16 + ln) * HD + lg * 8);

    const unsigned short* kb = g_kb + (size_t)bh * NN * HD;
    const unsigned short* tb = tin  + (size_t)bh * HD * NN;

    const f32x4 zero = {0.f, 0.f, 0.f, 0.f};
    f32x4 oacc[4][2];
    #pragma unroll
    for (int qi = 0; qi < 4; ++qi) { oacc[qi][0] = zero; oacc[qi][1] = zero; }
    float lsum[4] = {0.f, 0.f, 0.f, 0.f};

#if __has_builtin(__builtin_amdgcn_mfma_f32_16x16x16bf16_1k)
    for (int it = 0; it < 8; ++it) {
        const int k0 = it * 256 + w * 64;   // this wave's 64-key strip

        short8 kf[4];
        #pragma unroll
        for (int c = 0; c < 4; ++c)
            kf[c] = *(const short8*)(kb + (size_t)(k0 + c * 16 + ln) * HD + lg * 8);

        // T^T A-frags for K=16 PV: [c=key-chunk][hf=dim-half], 8B each
        short4v tf[4][2];
        #pragma unroll
        for (int c = 0; c < 4; ++c)
            #pragma unroll
            for (int hf = 0; hf < 2; ++hf)
                tf[c][hf] = *(const short4v*)(tb +
                    (size_t)(hf * 16 + ln) * NN + k0 + c * 16 + lg * 4);

        #pragma unroll
        for (int qi = 0; qi < 4; ++qi) {
            f32x4 s[4];
            #pragma unroll
            for (int c = 0; c < 4; ++c)
                s[c] = __builtin_amdgcn_mfma_f32_16x16x32_bf16(kf[c], qf[qi], zero, 0, 0, 0);
            float p[16];
            #pragma unroll
            for (int c = 0; c < 4; ++c)
                #pragma unroll
                for (int r = 0; r < 4; ++r)
                    p[c * 4 + r] = __builtin_amdgcn_exp2f(s[c][r]);
            if (KIND == 0) {
                #pragma unroll
                for (int e = 0; e < 16; ++e) lsum[qi] += p[e];
            }
            #pragma unroll
            for (int c = 0; c < 4; ++c) {
                union { unsigned int u[2]; short4v s; } pb;
                pb.u[0] = pk2(p[c * 4 + 0], p[c * 4 + 1]);
                pb.u[1] = pk2(p[c * 4 + 2], p[c * 4 + 3]);
                oacc[qi][0] = __builtin_amdgcn_mfma_f32_16x16x16bf16_1k(tf[c][0], pb.s, oacc[qi][0], 0, 0, 0);
                oacc[qi][1] = __builtin_amdgcn_mfma_f32_16x16x16bf16_1k(tf[c][1], pb.s, oacc[qi][1], 0, 0, 0);
            }
        }
    }
#else
    // fallback: r10's verified shuffle-transpose path (K=32 PV)
    for (int it = 0; it < 16; ++it) {
        const int k0 = it * 128 + w * 32;
        const short8 kf0 = *(const short8*)(kb + (size_t)(k0 + ln) * HD + lg * 8);
        const short8 kf1 = *(const short8*)(kb + (size_t)(k0 + 16 + ln) * HD + lg * 8);
        const short8 tf0 = *(const short8*)(tb + (size_t)ln * NN + k0 + lg * 8);
        const short8 tf1 = *(const short8*)(tb + (size_t)(ln + 16) * NN + k0 + lg * 8);
        #pragma unroll
        for (int qi = 0; qi < 4; ++qi) {
            f32x4 s0 = __builtin_amdgcn_mfma_f32_16x16x32_bf16(kf0, qf[qi], zero, 0, 0, 0);
            f32x4 s1 = __builtin_amdgcn_mfma_f32_16x16x32_bf16(kf1, qf[qi], zero, 0, 0, 0);
            float p[8];
            #pragma unroll
            for (int r = 0; r < 4; ++r) {
                p[r]     = __builtin_amdgcn_exp2f(s0[r]);
                p[4 + r] = __builtin_amdgcn_exp2f(s1[r]);
                lsum[qi] += p[r] + p[4 + r];
            }
            const unsigned int pk0 = pk2(p[0], p[1]);
            const unsigned int pk1 = pk2(p[2], p[3]);
            const unsigned int pk2v = pk2(p[4], p[5]);
            const unsigned int pk3 = pk2(p[6], p[7]);
            int bi[4];
            #pragma unroll
            for (int j = 0; j < 4; ++j) {
                const int srcLane = (((2 * lg + (j >> 1)) & 3) << 4) + ln;
                const int lo = __shfl((j & 1) ? (int)pk1 : (int)pk0, srcLane, 64);
                const int hi = __shfl((j & 1) ? (int)pk3 : (int)pk2v, srcLane, 64);
                bi[j] = (lg < 2) ? lo : hi;
            }
            union { int i[4]; short8 s; } pf;
            pf.i[0] = bi[0]; pf.i[1] = bi[1]; pf.i[2] = bi[2]; pf.i[3] = bi[3];
            oacc[qi][0] = __builtin_amdgcn_mfma_f32_16x16x32_bf16(tf0, pf.s, oacc[qi][0], 0, 0, 0);
            oacc[qi][1] = __builtin_amdgcn_mfma_f32_16x16x32_bf16(tf1, pf.s, oacc[qi][1], 0, 0, 0);
        }
    }
#endif

    // lsum: reduce across lg groups (lanes sharing ln)
    if (KIND == 0) {
        #pragma unroll
        for (int qi = 0; qi < 4; ++qi) {
            lsum[qi] += __shfl_xor(lsum[qi], 16, 64);
            lsum[qi] += __shfl_xor(lsum[qi], 32, 64);
        }
        if (lg == 0) {
            #pragma unroll
            for (int qi = 0; qi < 4; ++qi) lsh[w][qi * 16 + ln] = lsum[qi];
        }
    }

    // store O^T wave-partials: row q = qi*16+ln, col d = hf*16+lg*4+r
    #pragma unroll
    for (int qi = 0; qi < 4; ++qi)
        #pragma unroll
        for (int hf = 0; hf < 2; ++hf)
            #pragma unroll
            for (int r = 0; r < 4; ++r)
                osh[w][qi * 16 + ln][hf * 16 + lg * 4 + r] = oacc[qi][hf][r];
    __syncthreads();

    // combine 4 wave-partials; thread t: q = t&63, dims (t>>6)*8 ..+7
    {
        const int q  = tid & 63;
        const int db = (tid >> 6) * 8;
        float invl;
        if (KIND == 0) {
            invl = 1.0f / (lsh[0][q] + lsh[1][q] + lsh[2][q] + lsh[3][q]);
            if (db == 0) g_invl[(size_t)bh * NN + q0 + q] = invl;
        } else {
            invl = g_invl[(size_t)bh * NN + q0 + q];
        }
        const float ck = g_cf[h * 4 + kidx];
        #pragma unroll
        for (int dd = 0; dd < 8; ++dd) {
            const int d = db + dd;
            const float val = (osh[0][q][d] + osh[1][q][d] +
                               osh[2][q][d] + osh[3][q][d]) * invl;
            if (KIND != 2)
                tout[((size_t)bh * HD + d) * NN + q0 + q] = f2b(val);
            float* ga = g_acc + ((size_t)(b * NN + q0 + q)) * DD + h * HD + d;
            *ga += ck * val;
        }
    }
}

// ---------------------------------------------------------------------------
// Kernel 3: output projection GEMM (unchanged).
// ---------------------------------------------------------------------------
__global__ __launch_bounds__(256) void out_gemm_kernel(void* __restrict__ out)
{
    __shared__ unsigned short xs[64 * 32];
    __shared__ unsigned short wl[64 * 32];
    const int f32m = g_isf32;
    const int t  = threadIdx.x;
    const int w  = t >> 6, l = t & 63, lg = l >> 4, ln = l & 15;
    const int r0 = blockIdx.x * 64;
    const int n0 = blockIdx.y * 64;
    const unsigned short* wt = g_wt + 3 * DD * DD;
    const int sr = t >> 2, sc = (t & 3) * 8;

    f32x4 acc[4] = {{0,0,0,0},{0,0,0,0},{0,0,0,0},{0,0,0,0}};

    for (int kc = 0; kc < DD; kc += 32) {
        __syncthreads();
        {
            const float* src = g_acc + (size_t)(r0 + sr) * DD + kc + sc;
            const float4 a = *(const float4*)src;
            const float4 b = *(const float4*)(src + 4);
            union { uint4 v; unsigned short s[8]; } o;
            o.s[0]=f2b(a.x); o.s[1]=f2b(a.y); o.s[2]=f2b(a.z); o.s[3]=f2b(a.w);
            o.s[4]=f2b(b.x); o.s[5]=f2b(b.y); o.s[6]=f2b(b.z); o.s[7]=f2b(b.w);
            *(uint4*)(xs + sr * 32 + sc) = o.v;
        }
        *(uint4*)(wl + sr * 32 + sc) =
            *(const uint4*)(wt + (size_t)(n0 + sr) * DD + kc + sc);
        __syncthreads();
        const short8 af = *(const short8*)(xs + (w * 16 + ln) * 32 + lg * 8);
        #pragma unroll
        for (int s = 0; s < 4; ++s) {
            const short8 bfr = *(const short8*)(wl + (s * 16 + ln) * 32 + lg * 8);
            acc[s] = __builtin_amdgcn_mfma_f32_16x16x32_bf16(af, bfr, acc[s], 0, 0, 0);
        }
    }

    #pragma unroll
    for (int s = 0; s < 4; ++s) {
        const int j = n0 + s * 16 + ln;
        const float bias = g_bias[3 * DD + j];
        #pragma unroll
        for (int r = 0; r < 4; ++r) {
            const int rn = r0 + w * 16 + lg * 4 + r;
            const float val = acc[s][r] + bias;
            if (f32m) ((float*)out)[(size_t)rn * DD + j] = val;
            else      ((bf16*)out)[(size_t)rn * DD + j] = __float2bfloat16(val);
        }
    }
}

// ---------------------------------------------------------------------------
extern "C" void kernel_launch(void* const* d_in, const int* in_sizes, int n_in,
                              void* d_out, int out_size, void* d_ws, size_t ws_size,
                              hipStream_t stream)
{
    const void* x      = d_in[0];
    const void* Wq     = d_in[1];
    const void* bq     = d_in[2];
    const void* Wk     = d_in[3];
    const void* bk     = d_in[4];
    const void* Wv     = d_in[5];
    const void* bv     = d_in[6];
    const void* Wo     = d_in[7];
    const void* bo     = d_in[8];
    const void* coeffs = d_in[9];
    (void)d_ws; (void)ws_size; (void)in_sizes; (void)n_in; (void)out_size;

    probe_kernel<<<1, 256, 0, stream>>>(x);

    prep_w_kernel<<<dim3(16, 4), 256, 0, stream>>>(Wq, Wk, Wv, Wo,
                                                   bq, bk, bv, bo, coeffs);

    qkv_gemm_kernel<<<dim3(128, 4, 3), 256, 0, stream>>>(x);

    const int agrid = (BB * HH) * (NN / 64);   // 32 * 32 = 1024 blocks
    attn_pass_kernel<0><<<agrid, 256, 0, stream>>>(1, 0); // tA -> tB, caches invl
    attn_pass_kernel<1><<<agrid, 256, 0, stream>>>(2, 1); // tB -> tA, uses invl
    attn_pass_kernel<2><<<agrid, 256, 0, stream>>>(3, 0); // tA -> (acc only)

    out_gemm_kernel<<<dim3(128, 4), 256, 0, stream>>>(d_out);
}

// Round 4
// 239.743 us; speedup vs baseline: 1.5082x; 1.1719x over previous
//
#include <hip/hip_runtime.h>
#include <hip/hip_bf16.h>

typedef __hip_bfloat16 bf16;
typedef __attribute__((ext_vector_type(8))) short short8;   // 8 bf16 = 4 VGPRs
typedef __attribute__((ext_vector_type(4))) short short4v;  // 4 bf16 = 2 VGPRs
typedef __attribute__((ext_vector_type(4))) float f32x4;    // MFMA C/D

#define BB 4
#define NN 2048
#define DD 256
#define HH 8
#define HD 32
#define BN (BB*NN)          // 8192
#define ELEMS (BN*DD)       // 2097152

// ---------------------------------------------------------------------------
// Scratch in module .bss (~25 MB).
// ---------------------------------------------------------------------------
__device__ int g_isf32;
__device__ __attribute__((aligned(256))) unsigned short g_qb [ELEMS]; // [bh][n][d] bf16 (pre-scaled)
__device__ __attribute__((aligned(256))) unsigned short g_kb [ELEMS]; // [bh][n][d] bf16
__device__ __attribute__((aligned(256))) unsigned short g_tA [ELEMS]; // [bh][d][n] bf16
__device__ __attribute__((aligned(256))) unsigned short g_tB [ELEMS]; // [bh][d][n] bf16
__device__ __attribute__((aligned(256))) float          g_acc[ELEMS]; // [b][n][D] f32
__device__ __attribute__((aligned(256))) unsigned short g_wt [4*DD*DD]; // W^T bf16 [mat][n][k]
__device__ __attribute__((aligned(256))) float g_bias[4*DD];
__device__ __attribute__((aligned(256))) float g_cf[HH*4];
__device__ __attribute__((aligned(256))) float g_invl[BB*HH*NN];      // cached 1/rowsum (pass 1)

__device__ __forceinline__ float b2f(unsigned short u) {
    union { unsigned int i; float f; } c; c.i = ((unsigned int)u) << 16; return c.f;
}
__device__ __forceinline__ unsigned short f2b(float f) {           // safe path
    bf16 h = __float2bfloat16(f);
    return *reinterpret_cast<unsigned short*>(&h);
}
// pack two f32 -> one u32 of two bf16 (RNE).  gfx950 has a 1-instr pk cvt.
#if __has_builtin(__builtin_amdgcn_cvt_pk_bf16_f32)
typedef __attribute__((ext_vector_type(2))) __bf16 bf16x2t;
__device__ __forceinline__ unsigned int pk2(float a, float b) {
    union { bf16x2t v; unsigned int u; } c;
    c.v = __builtin_amdgcn_cvt_pk_bf16_f32(a, b);
    return c.u;
}
#else
__device__ __forceinline__ unsigned int pk2(float a, float b) {
    unsigned int ua = __float_as_uint(a), ub = __float_as_uint(b);
    ua = (ua + 0x7FFFu + ((ua >> 16) & 1u)) >> 16;
    ub = (ub + 0x7FFFu + ((ub >> 16) & 1u)) & 0xFFFF0000u;
    return ua | ub;
}
#endif
__device__ __forceinline__ float ldin(const void* p, int i, int f32m) {
    return f32m ? ((const float*)p)[i] : b2f(((const unsigned short*)p)[i]);
}

// ---------------------------------------------------------------------------
// Kernel 0: dtype probe (unchanged — verified rounds 4-10).
// ---------------------------------------------------------------------------
__global__ __launch_bounds__(256) void probe_kernel(const void* __restrict__ x)
{
    __shared__ int cnt;
    if (threadIdx.x == 0) cnt = 0;
    __syncthreads();
    const unsigned short* u = (const unsigned short*)x;
    int w = 0;
    for (int i = threadIdx.x; i < 1024; i += 256) {
        const int e = (u[2 * i] >> 7) & 0xFF;
        if (e < 100 || e > 140) ++w;
    }
    atomicAdd(&cnt, w);
    __syncthreads();
    if (threadIdx.x == 0) g_isf32 = (cnt > 300) ? 1 : 0;
}

// ---------------------------------------------------------------------------
// Prep: transpose W[k][n] -> g_wt[mat][n][k] bf16; block(0,0) also preps
// biases + coeffs to f32.
// ---------------------------------------------------------------------------
__global__ __launch_bounds__(256) void prep_w_kernel(
    const void* W0, const void* W1, const void* W2, const void* W3,
    const void* bq, const void* bk, const void* bv, const void* bo,
    const void* coeffs)
{
    const int f32m = g_isf32;
    __shared__ unsigned short tile[64][65];
    const int mat = blockIdx.y;
    const void* W = (mat == 0) ? W0 : (mat == 1) ? W1 : (mat == 2) ? W2 : W3;
    const int k0 = (blockIdx.x >> 2) * 64;
    const int n0 = (blockIdx.x & 3) * 64;
    const int t  = threadIdx.x;

    if (blockIdx.x == 0 && blockIdx.y == 0) {
        g_bias[0 * DD + t] = ldin(bq, t, f32m);
        g_bias[1 * DD + t] = ldin(bk, t, f32m);
        g_bias[2 * DD + t] = ldin(bv, t, f32m);
        g_bias[3 * DD + t] = ldin(bo, t, f32m);
        if (t < 32) g_cf[t] = ldin(coeffs, t, f32m);
    }

    #pragma unroll
    for (int it = 0; it < 16; ++it) {
        const int flat = it * 256 + t;
        const int i = flat >> 6, j = flat & 63;
        tile[j][i] = f2b(ldin(W, (k0 + i) * DD + n0 + j, f32m));
    }
    __syncthreads();
    unsigned short* wt = g_wt + mat * DD * DD;
    #pragma unroll
    for (int it = 0; it < 16; ++it) {
        const int flat = it * 256 + t;
        const int nl = flat >> 6, kl = flat & 63;
        wt[(n0 + nl) * DD + k0 + kl] = tile[nl][kl];
    }
}

// ---------------------------------------------------------------------------
// Kernel 1: QKV projection GEMM (unchanged from r10).
// ---------------------------------------------------------------------------
__global__ __launch_bounds__(256) void qkv_gemm_kernel(const void* __restrict__ x)
{
    __shared__ unsigned short xs[64 * 32];
    __shared__ unsigned short wl[64 * 32];
    const int f32m = g_isf32;
    const int t  = threadIdx.x;
    const int w  = t >> 6, l = t & 63, lg = l >> 4, ln = l & 15;
    const int r0 = blockIdx.x * 64;
    const int n0 = blockIdx.y * 64;
    const int mat = blockIdx.z;
    const unsigned short* wt = g_wt + mat * DD * DD;
    const int sr = t >> 2, sc = (t & 3) * 8;

    f32x4 acc[4] = {{0,0,0,0},{0,0,0,0},{0,0,0,0},{0,0,0,0}};

    for (int kc = 0; kc < DD; kc += 32) {
        __syncthreads();
        if (f32m) {
            const float* src = (const float*)x + (size_t)(r0 + sr) * DD + kc + sc;
            const float4 a = *(const float4*)src;
            const float4 b = *(const float4*)(src + 4);
            union { uint4 v; unsigned short s[8]; } o;
            o.s[0]=f2b(a.x); o.s[1]=f2b(a.y); o.s[2]=f2b(a.z); o.s[3]=f2b(a.w);
            o.s[4]=f2b(b.x); o.s[5]=f2b(b.y); o.s[6]=f2b(b.z); o.s[7]=f2b(b.w);
            *(uint4*)(xs + sr * 32 + sc) = o.v;
        } else {
            *(uint4*)(xs + sr * 32 + sc) =
                *(const uint4*)((const unsigned short*)x + (size_t)(r0 + sr) * DD + kc + sc);
        }
        *(uint4*)(wl + sr * 32 + sc) =
            *(const uint4*)(wt + (size_t)(n0 + sr) * DD + kc + sc);
        __syncthreads();
        const short8 af = *(const short8*)(xs + (w * 16 + ln) * 32 + lg * 8);
        #pragma unroll
        for (int s = 0; s < 4; ++s) {
            const short8 bfr = *(const short8*)(wl + (s * 16 + ln) * 32 + lg * 8);
            acc[s] = __builtin_amdgcn_mfma_f32_16x16x32_bf16(af, bfr, acc[s], 0, 0, 0);
        }
    }

    const float QS = 0.17677669529663687f * 1.4426950408889634f; // scale*log2e
    #pragma unroll
    for (int s = 0; s < 4; ++s) {
        const int j = n0 + s * 16 + ln;
        const float bias = g_bias[mat * DD + j];
        const int h = j >> 5, dd = j & 31;
        #pragma unroll
        for (int r = 0; r < 4; ++r) {
            const int rn = r0 + w * 16 + lg * 4 + r;
            const int b = rn >> 11, n = rn & (NN - 1);
            const int bh = b * HH + h;
            const float val = acc[s][r] + bias;
            if (mat == 0) {
                g_qb[((size_t)bh * NN + n) * HD + dd] = f2b(val * QS);
            } else if (mat == 1) {
                g_kb[((size_t)bh * NN + n) * HD + dd] = f2b(val);
            } else {
                g_tA[((size_t)bh * HD + dd) * NN + n] = f2b(val);
                g_acc[(size_t)rn * DD + j] = g_cf[h * 4] * val;
            }
        }
    }
}

// ---------------------------------------------------------------------------
// Kernel 2 (r15): attention pass = r11 loop body EXACTLY (VGPR=64, verified
// 53.8us) + two additions that don't touch the loop:
//  1. XCD-aware block swizzle: all 32 q-tile blocks of one bh land on the
//     same XCD (xcd = blockIdx%8 round-robin heuristic).  r11's FETCH_SIZE
//     was 39MB/pass vs ~13MB unique data -> per-XCD L2 thrash (each XCD
//     held ~16 bh working sets ~6MB > 4MB L2), HBM-latency stalls (~80%
//     issue idle).  After swizzle each XCD touches 4 bh (~1.5MB) -> K/T
//     L2-resident for the whole pass and across passes.
//  2. KIND specialization (verified r12): KIND=0 caches 1/rowsum to g_invl;
//     KIND=1/2 skip all row-sum work (32 fadds/it + shfl reduce) and load
//     cached invl; KIND=2 skips the dead tout store (-4MB writes).
// ---------------------------------------------------------------------------
template<int KIND>
__global__ __launch_bounds__(256) void attn_pass_kernel(const int kidx, const int dir)
{
    __shared__ float osh[4][64][33];   // [wave][q][d] (+1 pad)
    __shared__ float lsh[4][64];

    const unsigned short* __restrict__ tin  = dir ? g_tB : g_tA;
    unsigned short*       __restrict__ tout = dir ? g_tA : g_tB;

    const int tid = threadIdx.x;
    const int w   = tid >> 6;
    const int l   = tid & 63;
    const int lg  = l >> 4;
    const int ln  = l & 15;

    // XCD swizzle: bi%8 selects XCD (round-robin); give each XCD 4 bh.
    const int bi = blockIdx.x;                 // grid 1024
    const int bh = (bi & 7) * 4 + ((bi >> 3) & 3);   // b*H + h
    const int qt = bi >> 5;
    const int h  = bh & (HH - 1);
    const int b  = bh >> 3;
    const int q0 = qt * 64;

    short8 qf[4];
    #pragma unroll
    for (int qi = 0; qi < 4; ++qi)
        qf[qi] = *(const short8*)(g_qb +
            ((size_t)bh * NN + q0 + qi * 16 + ln) * HD + lg * 8);

    const unsigned short* kb = g_kb + (size_t)bh * NN * HD;
    const unsigned short* tb = tin  + (size_t)bh * HD * NN;

    f32x4 oacc[4][2];
    #pragma unroll
    for (int qi = 0; qi < 4; ++qi) { oacc[qi][0] = (f32x4){0,0,0,0}; oacc[qi][1] = (f32x4){0,0,0,0}; }
    float lsum[4] = {0.f, 0.f, 0.f, 0.f};
    const f32x4 zero = {0.f, 0.f, 0.f, 0.f};

    for (int it = 0; it < 16; ++it) {
        const int k0 = it * 128 + w * 32;   // this wave's 32-key strip
        const short8 kf0 = *(const short8*)(kb + (size_t)(k0 + ln) * HD + lg * 8);
        const short8 kf1 = *(const short8*)(kb + (size_t)(k0 + 16 + ln) * HD + lg * 8);

#if __has_builtin(__builtin_amdgcn_mfma_f32_16x16x16bf16_1k)
        // T^T A-frags for K=16 PV: [c=key-chunk][hf=dim-half], 8B each
        short4v tf[2][2];
        #pragma unroll
        for (int c = 0; c < 2; ++c)
            #pragma unroll
            for (int hf = 0; hf < 2; ++hf)
                tf[c][hf] = *(const short4v*)(tb +
                    (size_t)(hf * 16 + ln) * NN + k0 + c * 16 + lg * 4);

        #pragma unroll
        for (int qi = 0; qi < 4; ++qi) {
            f32x4 s0 = __builtin_amdgcn_mfma_f32_16x16x32_bf16(kf0, qf[qi], zero, 0, 0, 0);
            f32x4 s1 = __builtin_amdgcn_mfma_f32_16x16x32_bf16(kf1, qf[qi], zero, 0, 0, 0);
            float p[8];
            #pragma unroll
            for (int r = 0; r < 4; ++r) {
                p[r]     = __builtin_amdgcn_exp2f(s0[r]);
                p[4 + r] = __builtin_amdgcn_exp2f(s1[r]);
                if (KIND == 0) lsum[qi] += p[r] + p[4 + r];
            }
            union { unsigned int u[2]; short4v s; } pb0, pb1;
            pb0.u[0] = pk2(p[0], p[1]); pb0.u[1] = pk2(p[2], p[3]);
            pb1.u[0] = pk2(p[4], p[5]); pb1.u[1] = pk2(p[6], p[7]);
            oacc[qi][0] = __builtin_amdgcn_mfma_f32_16x16x16bf16_1k(tf[0][0], pb0.s, oacc[qi][0], 0, 0, 0);
            oacc[qi][1] = __builtin_amdgcn_mfma_f32_16x16x16bf16_1k(tf[0][1], pb0.s, oacc[qi][1], 0, 0, 0);
            oacc[qi][0] = __builtin_amdgcn_mfma_f32_16x16x16bf16_1k(tf[1][0], pb1.s, oacc[qi][0], 0, 0, 0);
            oacc[qi][1] = __builtin_amdgcn_mfma_f32_16x16x16bf16_1k(tf[1][1], pb1.s, oacc[qi][1], 0, 0, 0);
        }
#else
        // fallback: r10's verified shuffle-transpose path (K=32 PV)
        const short8 tf0 = *(const short8*)(tb + (size_t)ln * NN + k0 + lg * 8);
        const short8 tf1 = *(const short8*)(tb + (size_t)(ln + 16) * NN + k0 + lg * 8);
        #pragma unroll
        for (int qi = 0; qi < 4; ++qi) {
            f32x4 s0 = __builtin_amdgcn_mfma_f32_16x16x32_bf16(kf0, qf[qi], zero, 0, 0, 0);
            f32x4 s1 = __builtin_amdgcn_mfma_f32_16x16x32_bf16(kf1, qf[qi], zero, 0, 0, 0);
            float p[8];
            #pragma unroll
            for (int r = 0; r < 4; ++r) {
                p[r]     = __builtin_amdgcn_exp2f(s0[r]);
                p[4 + r] = __builtin_amdgcn_exp2f(s1[r]);
                if (KIND == 0) lsum[qi] += p[r] + p[4 + r];
            }
            const unsigned int pk0 = pk2(p[0], p[1]);
            const unsigned int pk1 = pk2(p[2], p[3]);
            const unsigned int pk2v = pk2(p[4], p[5]);
            const unsigned int pk3 = pk2(p[6], p[7]);
            int bi2[4];
            #pragma unroll
            for (int j = 0; j < 4; ++j) {
                const int srcLane = (((2 * lg + (j >> 1)) & 3) << 4) + ln;
                const int lo = __shfl((j & 1) ? (int)pk1 : (int)pk0, srcLane, 64);
                const int hi = __shfl((j & 1) ? (int)pk3 : (int)pk2v, srcLane, 64);
                bi2[j] = (lg < 2) ? lo : hi;
            }
            union { int i[4]; short8 s; } pf;
            pf.i[0] = bi2[0]; pf.i[1] = bi2[1]; pf.i[2] = bi2[2]; pf.i[3] = bi2[3];
            oacc[qi][0] = __builtin_amdgcn_mfma_f32_16x16x32_bf16(tf0, pf.s, oacc[qi][0], 0, 0, 0);
            oacc[qi][1] = __builtin_amdgcn_mfma_f32_16x16x32_bf16(tf1, pf.s, oacc[qi][1], 0, 0, 0);
        }
#endif
    }

    // lsum: reduce across lg groups (lanes sharing ln) — pass 1 only
    if (KIND == 0) {
        #pragma unroll
        for (int qi = 0; qi < 4; ++qi) {
            lsum[qi] += __shfl_xor(lsum[qi], 16, 64);
            lsum[qi] += __shfl_xor(lsum[qi], 32, 64);
        }
        if (lg == 0) {
            #pragma unroll
            for (int qi = 0; qi < 4; ++qi) lsh[w][qi * 16 + ln] = lsum[qi];
        }
    }

    // store O^T wave-partials: row q = qi*16+ln, col d = hf*16+lg*4+r
    #pragma unroll
    for (int qi = 0; qi < 4; ++qi)
        #pragma unroll
        for (int hf = 0; hf < 2; ++hf)
            #pragma unroll
            for (int r = 0; r < 4; ++r)
                osh[w][qi * 16 + ln][hf * 16 + lg * 4 + r] = oacc[qi][hf][r];
    __syncthreads();

    // combine 4 wave-partials; thread t: q = t&63, dims (t>>6)*8 ..+7
    {
        const int q  = tid & 63;
        const int db = (tid >> 6) * 8;
        float invl;
        if (KIND == 0) {
            invl = 1.0f / (lsh[0][q] + lsh[1][q] + lsh[2][q] + lsh[3][q]);
            if (db == 0) g_invl[(size_t)bh * NN + q0 + q] = invl;
        } else {
            invl = g_invl[(size_t)bh * NN + q0 + q];
        }
        const float ck = g_cf[h * 4 + kidx];
        #pragma unroll
        for (int dd = 0; dd < 8; ++dd) {
            const int d = db + dd;
            const float val = (osh[0][q][d] + osh[1][q][d] +
                               osh[2][q][d] + osh[3][q][d]) * invl;
            if (KIND != 2)
                tout[((size_t)bh * HD + d) * NN + q0 + q] = f2b(val);
            float* ga = g_acc + ((size_t)(b * NN + q0 + q)) * DD + h * HD + d;
            *ga += ck * val;
        }
    }
}

// ---------------------------------------------------------------------------
// Kernel 3: output projection GEMM (unchanged).
// ---------------------------------------------------------------------------
__global__ __launch_bounds__(256) void out_gemm_kernel(void* __restrict__ out)
{
    __shared__ unsigned short xs[64 * 32];
    __shared__ unsigned short wl[64 * 32];
    const int f32m = g_isf32;
    const int t  = threadIdx.x;
    const int w  = t >> 6, l = t & 63, lg = l >> 4, ln = l & 15;
    const int r0 = blockIdx.x * 64;
    const int n0 = blockIdx.y * 64;
    const unsigned short* wt = g_wt + 3 * DD * DD;
    const int sr = t >> 2, sc = (t & 3) * 8;

    f32x4 acc[4] = {{0,0,0,0},{0,0,0,0},{0,0,0,0},{0,0,0,0}};

    for (int kc = 0; kc < DD; kc += 32) {
        __syncthreads();
        {
            const float* src = g_acc + (size_t)(r0 + sr) * DD + kc + sc;
            const float4 a = *(const float4*)src;
            const float4 b = *(const float4*)(src + 4);
            union { uint4 v; unsigned short s[8]; } o;
            o.s[0]=f2b(a.x); o.s[1]=f2b(a.y); o.s[2]=f2b(a.z); o.s[3]=f2b(a.w);
            o.s[4]=f2b(b.x); o.s[5]=f2b(b.y); o.s[6]=f2b(b.z); o.s[7]=f2b(b.w);
            *(uint4*)(xs + sr * 32 + sc) = o.v;
        }
        *(uint4*)(wl + sr * 32 + sc) =
            *(const uint4*)(wt + (size_t)(n0 + sr) * DD + kc + sc);
        __syncthreads();
        const short8 af = *(const short8*)(xs + (w * 16 + ln) * 32 + lg * 8);
        #pragma unroll
        for (int s = 0; s < 4; ++s) {
            const short8 bfr = *(const short8*)(wl + (s * 16 + ln) * 32 + lg * 8);
            acc[s] = __builtin_amdgcn_mfma_f32_16x16x32_bf16(af, bfr, acc[s], 0, 0, 0);
        }
    }

    #pragma unroll
    for (int s = 0; s < 4; ++s) {
        const int j = n0 + s * 16 + ln;
        const float bias = g_bias[3 * DD + j];
        #pragma unroll
        for (int r = 0; r < 4; ++r) {
            const int rn = r0 + w * 16 + lg * 4 + r;
            const float val = acc[s][r] + bias;
            if (f32m) ((float*)out)[(size_t)rn * DD + j] = val;
            else      ((bf16*)out)[(size_t)rn * DD + j] = __float2bfloat16(val);
        }
    }
}

// ---------------------------------------------------------------------------
extern "C" void kernel_launch(void* const* d_in, const int* in_sizes, int n_in,
                              void* d_out, int out_size, void* d_ws, size_t ws_size,
                              hipStream_t stream)
{
    const void* x      = d_in[0];
    const void* Wq     = d_in[1];
    const void* bq     = d_in[2];
    const void* Wk     = d_in[3];
    const void* bk     = d_in[4];
    const void* Wv     = d_in[5];
    const void* bv     = d_in[6];
    const void* Wo     = d_in[7];
    const void* bo     = d_in[8];
    const void* coeffs = d_in[9];
    (void)d_ws; (void)ws_size; (void)in_sizes; (void)n_in; (void)out_size;

    probe_kernel<<<1, 256, 0, stream>>>(x);

    prep_w_kernel<<<dim3(16, 4), 256, 0, stream>>>(Wq, Wk, Wv, Wo,
                                                   bq, bk, bv, bo, coeffs);

    qkv_gemm_kernel<<<dim3(128, 4, 3), 256, 0, stream>>>(x);

    const int agrid = (BB * HH) * (NN / 64);   // 32 * 32 = 1024 blocks
    attn_pass_kernel<0><<<agrid, 256, 0, stream>>>(1, 0); // tA -> tB, caches invl
    attn_pass_kernel<1><<<agrid, 256, 0, stream>>>(2, 1); // tB -> tA, uses invl
    attn_pass_kernel<2><<<agrid, 256, 0, stream>>>(3, 0); // tA -> (acc only)

    out_gemm_kernel<<<dim3(128, 4), 256, 0, stream>>>(d_out);
}